// Round 14
// baseline (494.868 us; speedup 1.0000x reference)
//
#include <hip/hip_runtime.h>
#include <stdint.h>

#define Bz 32
#define Nz 4096
#define Lz 512
#define Mz (Bz*Nz)   // 131072 rows
#define BM 32        // rows per tile
#define TPB 8        // tiles per block
#define NBLK 512     // blocks (Mz/BM/TPB)

typedef __attribute__((ext_vector_type(8))) short bf16x8;
typedef __attribute__((ext_vector_type(4))) float f32x4;
typedef __attribute__((ext_vector_type(4))) float nf4;

__device__ __forceinline__ uint32_t f2bf(float f) {
    union { float f; uint32_t u; } v; v.f = f;
    uint32_t u = v.u;
    u += 0x7FFFu + ((u >> 16) & 1u);   // RNE
    return u >> 16;
}
__device__ __forceinline__ uint32_t pk2(float a, float b) {
    uint32_t r;
    asm("v_cvt_pk_bf16_f32 %0, %1, %2" : "=v"(r) : "v"(a), "v"(b));
    return r;
}
__device__ __forceinline__ float rcp_(float x) { return __builtin_amdgcn_rcpf(x); }
__device__ __forceinline__ float bf2f(uint32_t u) {
    union { uint32_t u; float f; } v; v.u = u << 16; return v.f;
}

// lgkm-only barrier: NT stores / prefetch loads stay in flight (no vmcnt drain)
#define LGKM_BAR() asm volatile("s_waitcnt lgkmcnt(0)\n\ts_barrier" ::: "memory")

// ---------------------------------------------------------------------------
// Kernel 0: pack [Wa | Wb] bf16 B-fragments (validated r5-r13).
// idx = ((kt*8 + wv)*4 + cf)*64 + lane; a-ctile 2wv+cf, g-ctile 16+2wv+(cf-2).
// ---------------------------------------------------------------------------
__global__ void pack_w(const float* __restrict__ Wa, const float* __restrict__ Wb,
                       unsigned short* __restrict__ packed)
{
    int tid  = blockIdx.x * blockDim.x + threadIdx.x;
    int lane = tid & 63;
    int cf   = (tid >> 6) & 3;
    int wv   = (tid >> 8) & 7;
    int kt   = tid >> 11;
    int ctile = (cf < 2) ? (2 * wv + cf) : (16 + 2 * wv + (cf - 2));
    int k0  = kt * 32 + ((lane >> 4) << 3);
    int col = ctile * 16 + (lane & 15);
    const float* W = (col < 256) ? Wa : Wb;
    int c = col & 255;
    bf16x8 v;
    #pragma unroll
    for (int j = 0; j < 8; ++j) v[j] = (short)f2bf(W[(k0 + j) * 256 + c]);
    *(bf16x8*)(&packed[(size_t)tid * 8]) = v;
}

// stage-convert: f[4] (fp32) -> swizzled bf16 LDS tile (1024 threads, BM=32)
__device__ __forceinline__ void cvt_tile(const nf4 (&f)[4], char* base, int t)
{
    #pragma unroll
    for (int i = 0; i < 2; ++i) {
        int lin = i * 2048 + 2 * t;
        int r = lin >> 7, c16 = (lin & 127) >> 1;
        uint32_t off = (uint32_t)(r * 1024 + c16 * 16) ^ (uint32_t)((r & 7) << 4);
        uint4 w;
        w.x = pk2(f[2*i].x, f[2*i].y);     w.y = pk2(f[2*i].z, f[2*i].w);
        w.z = pk2(f[2*i+1].x, f[2*i+1].y); w.w = pk2(f[2*i+1].z, f[2*i+1].w);
        *(uint4*)(base + off) = w;
    }
}

// ---------------------------------------------------------------------------
// One K-loop over a staged tile, with (optionally) the PREVIOUS tile's tail
// (epilogue/stats/pool) interleaved into the kt slots, next-tile loads spread
// at kt=4,7,10,13, and NT xcopy stores of the current tile at kt=2,6.
// ---------------------------------------------------------------------------
template<int TAILF, int LOADF>
__device__ __forceinline__ void kblock(
    f32x4 (&acc)[2][2], f32x4 (&tac)[2][2],
    nf4 (&fc)[4], nf4 (&fn)[4],
    const char* bufc, const char* bufp,
    nf4* __restrict__ xdc, const nf4* __restrict__ xn,
    int tilep, const bf16x8* __restrict__ bpw,
    uint32_t bE0, uint32_t bO0, uint32_t bE1, uint32_t bO1,
    float ba0, float bb0, float wc0, float bcv,
    int t, int wave, int lane, int lrow,
    float (&spart)[16][32],
    float* __restrict__ escore, float* __restrict__ ms,
    float* __restrict__ esums, float* __restrict__ vs2)
{
    #pragma unroll
    for (int a = 0; a < 2; ++a)
        #pragma unroll
        for (int b = 0; b < 2; ++b)
            acc[a][b] = (f32x4){0.f, 0.f, 0.f, 0.f};

    bf16x8 bv[2][2];
    bv[0][0] = bpw[0];
    bv[0][1] = bpw[128];

    float e = 0.f, pacc = 0.f;
    const int rg = t >> 9;          // 0/1 : pool rows rg*16..rg*16+15
    const int pc = t & 511;         // pool column

    #pragma unroll
    for (int kt = 0; kt < 16; ++kt) {
        if (kt < 15) {
            bv[(kt + 1) & 1][0] = bpw[(kt + 1) * 2048];
            bv[(kt + 1) & 1][1] = bpw[(kt + 1) * 2048 + 128];
        }
        if (kt == 2) {
            __builtin_nontemporal_store(fc[0], &xdc[2 * t]);
            __builtin_nontemporal_store(fc[1], &xdc[2 * t + 1]);
            __builtin_amdgcn_sched_barrier(0);
        }
        if (kt == 6) {
            __builtin_nontemporal_store(fc[2], &xdc[2048 + 2 * t]);
            __builtin_nontemporal_store(fc[3], &xdc[2048 + 2 * t + 1]);
            __builtin_amdgcn_sched_barrier(0);
        }
        if (LOADF) {
            if (kt == 4)  fn[0] = xn[2 * t];
            if (kt == 7)  fn[1] = xn[2 * t + 1];
            if (kt == 10) fn[2] = xn[2048 + 2 * t];
            if (kt == 13) fn[3] = xn[2048 + 2 * t + 1];
        }
        if (TAILF) {
            if (kt < 8) {               // epilogue chunk: one p-value
                const int rf = kt >> 2, r = kt & 3;
                float pa = tac[rf][0][r] + ba0;
                float pg = tac[rf][1][r] + bb0;
                float ea = __expf(-2.f * pa);
                float a0 = 1.f - 2.f * ea * rcp_(1.f + ea);   // tanh
                float g0 = rcp_(1.f + __expf(-pg));           // sigmoid
                float p = a0 * g0 * wc0;
                p += __shfl_xor(p, 1);
                p += __shfl_xor(p, 2);
                p += __shfl_xor(p, 4);
                p += __shfl_xor(p, 8);
                if (lrow == 0)
                    spart[wave][rf * 16 + ((lane >> 4) << 2) + r] = p;
            }
            if (kt == 9) LGKM_BAR();    // spart visible; vmcnt untouched
            if (kt == 10) {             // stats for tilep
                float s = bcv;
                #pragma unroll
                for (int w = 0; w < 16; ++w) s += spart[w][lane & 31];
                float m = s;
                #pragma unroll
                for (int o = 16; o; o >>= 1) m = fmaxf(m, __shfl_xor(m, o));
                e = __expf(s - m);
                float es = e;
                #pragma unroll
                for (int o = 16; o; o >>= 1) es += __shfl_xor(es, o);
                if (t < 32) escore[tilep * 32 + t] = e;
                if (t == 0) { ms[tilep] = m; esums[tilep] = es; }
                pacc = 0.f;
            }
            if (kt >= 11 && kt <= 14) { // pool: 4 rows per slot from bufp
                const int v = kt - 11;
                #pragma unroll
                for (int j = 0; j < 4; ++j) {
                    int row = rg * 16 + v * 4 + j;
                    float er = __shfl(e, row);
                    uint32_t off = (uint32_t)(row * 1024 + pc * 2)
                                 ^ (uint32_t)((row & 7) << 4);
                    unsigned short us = *(const unsigned short*)(bufp + off);
                    pacc += er * bf2f((uint32_t)us);
                }
            }
            if (kt == 15)
                vs2[((size_t)tilep * 2 + rg) * 512 + pc] = pacc;
        }
        bf16x8 av0 = *(const bf16x8*)(bufc + ((kt & 1) ? bO0 : bE0) + kt * 64);
        bf16x8 av1 = *(const bf16x8*)(bufc + ((kt & 1) ? bO1 : bE1) + kt * 64);
        acc[0][0] = __builtin_amdgcn_mfma_f32_16x16x32_bf16(av0, bv[kt & 1][0], acc[0][0], 0, 0, 0);
        acc[0][1] = __builtin_amdgcn_mfma_f32_16x16x32_bf16(av0, bv[kt & 1][1], acc[0][1], 0, 0, 0);
        acc[1][0] = __builtin_amdgcn_mfma_f32_16x16x32_bf16(av1, bv[kt & 1][0], acc[1][0], 0, 0, 0);
        acc[1][1] = __builtin_amdgcn_mfma_f32_16x16x32_bf16(av1, bv[kt & 1][1], acc[1][1], 0, 0, 0);
    }
}

// ---------------------------------------------------------------------------
// Kernel 1: 1024 threads (16 waves, 2 cf each), TPB=8 tiles, LDS double
// buffer, tail-interleaved pipeline, lgkm-only barriers.
// ---------------------------------------------------------------------------
__global__ __launch_bounds__(1024, 4) void fused_scores(
    const float* __restrict__ x, const unsigned short* __restrict__ packedW,
    const float* __restrict__ ba, const float* __restrict__ bb,
    const float* __restrict__ Wc, const float* __restrict__ bc,
    float* __restrict__ xcopy, float* __restrict__ escore,
    float* __restrict__ ms, float* __restrict__ esums,
    float* __restrict__ vs2)
{
    __shared__ unsigned short xlds0[BM * Lz];   // 32 KiB
    __shared__ unsigned short xlds1[BM * Lz];   // 32 KiB
    __shared__ float spart[16][32];

    const int blk  = blockIdx.x;
    const int t    = threadIdx.x;
    const int wave = t >> 6;
    const int lane = t & 63;
    const int lrow = lane & 15;
    const int wvv  = wave >> 1;
    const int asel = wave & 1;

    const bf16x8* bpw = (const bf16x8*)packedW + ((wvv * 4 + asel) * 64 + lane);

    const uint32_t s45 = (uint32_t)((lrow & 3) << 4);
    const uint32_t s6  = (uint32_t)((lrow & 4) << 4);
    uint32_t b0 = (uint32_t)(lrow * 1024 + ((lane >> 4) << 4)) ^ s45;
    uint32_t b1 = (uint32_t)((16 + lrow) * 1024 + ((lane >> 4) << 4)) ^ s45;
    const uint32_t bE0 = b0 + s6, bO0 = b0 - s6;
    const uint32_t bE1 = b1 + s6, bO1 = b1 - s6;

    const int d0 = wave * 16 + lrow;            // 0..255
    const float ba0 = ba[d0], bb0 = bb[d0], wc0 = Wc[d0], bcv = bc[0];

    nf4 fA[4], fB[4];
    f32x4 accA[2][2], accB[2][2];

    const int t0 = blk * TPB;
    const nf4* xs = (const nf4*)x + (size_t)t0 * 4096;
    nf4*       xd = (nf4*)xcopy   + (size_t)t0 * 4096;

    // ---- prologue: stage tile 0 ----
    fA[0] = xs[2 * t]; fA[1] = xs[2 * t + 1];
    fA[2] = xs[2048 + 2 * t]; fA[3] = xs[2048 + 2 * t + 1];
    cvt_tile(fA, (char*)xlds0, t);
    __syncthreads();

    // ---- tile 0 (no tail) ----
    kblock<0, 1>(accA, accB, fA, fB, (const char*)xlds0, (const char*)xlds1,
                 xd, xs + 4096, 0, bpw, bE0, bO0, bE1, bO1,
                 ba0, bb0, wc0, bcv, t, wave, lane, lrow, spart,
                 escore, ms, esums, vs2);
    LGKM_BAR();
    cvt_tile(fB, (char*)xlds1, t);
    LGKM_BAR();

    for (int h = 0; h < 3; ++h) {
        const int to = 2 * h + 1, te = 2 * h + 2;
        kblock<1, 1>(accB, accA, fB, fA, (const char*)xlds1, (const char*)xlds0,
                     xd + (size_t)to * 4096, xs + (size_t)te * 4096,
                     t0 + to - 1, bpw, bE0, bO0, bE1, bO1,
                     ba0, bb0, wc0, bcv, t, wave, lane, lrow, spart,
                     escore, ms, esums, vs2);
        LGKM_BAR();
        cvt_tile(fA, (char*)xlds0, t);
        LGKM_BAR();
        kblock<1, 1>(accA, accB, fA, fB, (const char*)xlds0, (const char*)xlds1,
                     xd + (size_t)te * 4096, xs + (size_t)(te + 1) * 4096,
                     t0 + te - 1, bpw, bE0, bO0, bE1, bO1,
                     ba0, bb0, wc0, bcv, t, wave, lane, lrow, spart,
                     escore, ms, esums, vs2);
        LGKM_BAR();
        cvt_tile(fB, (char*)xlds1, t);
        LGKM_BAR();
    }

    // ---- tile 7 (tail of 6 embedded, no next load) ----
    kblock<1, 0>(accB, accA, fB, fA, (const char*)xlds1, (const char*)xlds0,
                 xd + (size_t)7 * 4096, xs, t0 + 6, bpw, bE0, bO0, bE1, bO1,
                 ba0, bb0, wc0, bcv, t, wave, lane, lrow, spart,
                 escore, ms, esums, vs2);

    // ---- standalone tail for tile 7 (acc in accB, buf xlds1) ----
    #pragma unroll
    for (int v = 0; v < 8; ++v) {
        const int rf = v >> 2, r = v & 3;
        float pa = accB[rf][0][r] + ba0;
        float pg = accB[rf][1][r] + bb0;
        float ea = __expf(-2.f * pa);
        float a0 = 1.f - 2.f * ea * rcp_(1.f + ea);
        float g0 = rcp_(1.f + __expf(-pg));
        float p = a0 * g0 * wc0;
        p += __shfl_xor(p, 1);
        p += __shfl_xor(p, 2);
        p += __shfl_xor(p, 4);
        p += __shfl_xor(p, 8);
        if (lrow == 0)
            spart[wave][rf * 16 + ((lane >> 4) << 2) + r] = p;
    }
    __syncthreads();
    {
        const int tilep = t0 + 7;
        float s = bcv;
        #pragma unroll
        for (int w = 0; w < 16; ++w) s += spart[w][lane & 31];
        float m = s;
        #pragma unroll
        for (int o = 16; o; o >>= 1) m = fmaxf(m, __shfl_xor(m, o));
        float e = __expf(s - m);
        float es = e;
        #pragma unroll
        for (int o = 16; o; o >>= 1) es += __shfl_xor(es, o);
        if (t < 32) escore[tilep * 32 + t] = e;
        if (t == 0) { ms[tilep] = m; esums[tilep] = es; }

        const int rg = t >> 9, pc = t & 511;
        float pacc = 0.f;
        #pragma unroll
        for (int i = 0; i < 16; ++i) {
            int row = rg * 16 + i;
            float er = __shfl(e, row);
            uint32_t off = (uint32_t)(row * 1024 + pc * 2)
                         ^ (uint32_t)((row & 7) << 4);
            unsigned short us = *(const unsigned short*)((const char*)xlds1 + off);
            pacc += er * bf2f((uint32_t)us);
        }
        vs2[((size_t)tilep * 2 + rg) * 512 + pc] = pacc;
    }
}

// ---------------------------------------------------------------------------
// Kernel 2: finalize (r9's validated version). 576 blocks x 256.
// 128 chunks (32 rows each) per bag.
// ---------------------------------------------------------------------------
__global__ __launch_bounds__(256) void finalize(
    const float* __restrict__ ms, const float* __restrict__ esums,
    const float* __restrict__ vs2, const float* __restrict__ escore,
    float* __restrict__ A, float* __restrict__ pooled)
{
    const int bid = blockIdx.x;
    const int t   = threadIdx.x;
    const bool isA = bid < 512;
    const int bag = isA ? (bid >> 4) : ((bid - 512) >> 1);
    __shared__ float alpha[128];

    if (t < 64) {
        float ma = ms[bag * 128 + t];
        float mb = ms[bag * 128 + 64 + t];
        float M = fmaxf(ma, mb);
        #pragma unroll
        for (int o = 32; o; o >>= 1) M = fmaxf(M, __shfl_xor(M, o));
        float ea = __expf(ma - M), eb = __expf(mb - M);
        float T = esums[bag * 128 + t] * ea + esums[bag * 128 + 64 + t] * eb;
        #pragma unroll
        for (int o = 32; o; o >>= 1) T += __shfl_xor(T, o);
        alpha[t]      = ea / T;
        alpha[64 + t] = eb / T;
    }
    __syncthreads();

    if (isA) {
        int n = (bid & 15) * 256 + t;
        A[(size_t)bag * Nz + n] = escore[(size_t)bag * Nz + n] * alpha[n >> 5];
    } else {
        int col = ((bid - 512) & 1) * 256 + t;
        const float* base = vs2 + ((size_t)bag * 256) * 512 + col;
        float acc = 0.f;
        #pragma unroll 4
        for (int c = 0; c < 128; ++c) {
            float al = alpha[c];
            acc += al * base[(size_t)(2 * c) * 512];
            acc += al * base[(size_t)(2 * c + 1) * 512];
        }
        pooled[(size_t)bag * 512 + col] = acc;
    }
}

// ---------------------------------------------------------------------------
extern "C" void kernel_launch(void* const* d_in, const int* in_sizes, int n_in,
                              void* d_out, int out_size, void* d_ws, size_t ws_size,
                              hipStream_t stream)
{
    const float* x  = (const float*)d_in[0];
    const float* Wa = (const float*)d_in[1];
    const float* ba = (const float*)d_in[2];
    const float* Wb = (const float*)d_in[3];
    const float* bb = (const float*)d_in[4];
    const float* Wc = (const float*)d_in[5];
    const float* bc = (const float*)d_in[6];

    float* out    = (float*)d_out;
    float* A      = out;
    float* xcopy  = out + (size_t)Mz;
    float* pooled = xcopy + (size_t)Mz * Lz;

    char* ws = (char*)d_ws;
    unsigned short* packed = (unsigned short*)ws;                 // 512 KiB
    float* escore = (float*)(ws + 524288);                        // 512 KiB
    float* ms     = (float*)(ws + 1048576);                       // 16 KiB
    float* esums  = (float*)(ws + 1048576 + 16384);               // 16 KiB
    float* vs2    = (float*)(ws + 1048576 + 32768);               // 16 MiB

    pack_w      <<<128, 256, 0, stream>>>(Wa, Wb, packed);
    fused_scores<<<NBLK, 1024, 0, stream>>>(x, packed, ba, bb, Wc, bc,
                                            xcopy, escore, ms, esums, vs2);
    finalize    <<<576, 256, 0, stream>>>(ms, esums, vs2, escore, A, pooled);
}

// Round 15
// 219.187 us; speedup vs baseline: 2.2577x; 2.2577x over previous
//
#include <hip/hip_runtime.h>
#include <stdint.h>

#define Bz 32
#define Nz 4096
#define Lz 512
#define Mz (Bz*Nz)   // 131072 rows
#define BM 32        // rows per block
#define NWG (Mz/BM)  // 4096 blocks

typedef __attribute__((ext_vector_type(8))) short bf16x8;
typedef __attribute__((ext_vector_type(4))) float f32x4;
typedef __attribute__((ext_vector_type(4))) float nf4;

__device__ __forceinline__ uint32_t f2bf(float f) {
    union { float f; uint32_t u; } v; v.f = f;
    uint32_t u = v.u;
    u += 0x7FFFu + ((u >> 16) & 1u);   // RNE
    return u >> 16;
}

__device__ __forceinline__ uint32_t pk2(float a, float b) {
    uint32_t r;
    asm("v_cvt_pk_bf16_f32 %0, %1, %2" : "=v"(r) : "v"(a), "v"(b));
    return r;
}

__device__ __forceinline__ float rcp_(float x) { return __builtin_amdgcn_rcpf(x); }
__device__ __forceinline__ float bf2f(uint32_t u) {
    union { uint32_t u; float f; } v; v.u = u << 16; return v.f;
}

// ---------------------------------------------------------------------------
// Kernel 0: pack [Wa | Wb] into bf16 B-fragments, contiguous per (kt, wave):
// packed[((kt*8 + wave)*4 + cf)*64 + lane]; cf 0/1 = a-coltiles 2w/2w+1,
// cf 2/3 = g-coltiles 16+2w/17+2w.   (unchanged, validated r5-r14)
// ---------------------------------------------------------------------------
__global__ void pack_w(const float* __restrict__ Wa, const float* __restrict__ Wb,
                       unsigned short* __restrict__ packed)
{
    int tid  = blockIdx.x * blockDim.x + threadIdx.x;   // 0..32767
    int lane = tid & 63;
    int cf   = (tid >> 6) & 3;
    int wv   = (tid >> 8) & 7;
    int kt   = tid >> 11;                               // 0..15
    int ctile = (cf < 2) ? (2 * wv + cf) : (16 + 2 * wv + (cf - 2));
    int k0  = kt * 32 + ((lane >> 4) << 3);
    int col = ctile * 16 + (lane & 15);
    const float* W = (col < 256) ? Wa : Wb;
    int c = col & 255;
    bf16x8 v;
    #pragma unroll
    for (int j = 0; j < 8; ++j) v[j] = (short)f2bf(W[(k0 + j) * 256 + c]);
    *(bf16x8*)(&packed[(size_t)tid * 8]) = v;
}

// ---------------------------------------------------------------------------
// Kernel 1: fused GEMM + gated scores + xcopy + pooled partials.
// r9 dataflow, register-lean for 6 waves/SIMD = 3 blocks/CU:
//  - stage r4-interleaved (load pair -> plain store pair -> cvt -> ds_write),
//    f transient (8 regs), NO NT (NT inflates writes at >2 streams/CU).
//  - K-loop pure: bv double-buffer + ds_read + MFMA (no store events).
// K-loop peak regs ~ acc32 + bv32 + av8 + addr12 ~ 84 <= 85.
// ---------------------------------------------------------------------------
__global__ __launch_bounds__(512, 6) void fused_scores(
    const float* __restrict__ x, const unsigned short* __restrict__ packedW,
    const float* __restrict__ ba, const float* __restrict__ bb,
    const float* __restrict__ Wc, const float* __restrict__ bc,
    float* __restrict__ xcopy, float* __restrict__ escore,
    float* __restrict__ ms, float* __restrict__ esums,
    float* __restrict__ vs2)
{
    __shared__ unsigned short xlds[BM * Lz];   // 32 KiB, XOR-swizzled bf16
    __shared__ float spart[8][BM];             // 1 KiB

    const int wg   = blockIdx.x;       // 0..4095
    const int row0 = wg * BM;
    const int t    = threadIdx.x;
    const int wave = t >> 6;
    const int lane = t & 63;
    const int lrow = lane & 15;

    // ---- prefetch kt=0 B fragments (hidden under stage) ----
    const bf16x8* bp = (const bf16x8*)packedW + (size_t)wave * 256 + lane;
    bf16x8 bv[2][4];
    #pragma unroll
    for (int cf = 0; cf < 4; ++cf) bv[0][cf] = bp[cf * 64];

    // ---- stage: interleaved load/store/cvt/ds_write, f transient ----
    const nf4* xsrc = (const nf4*)(x     + (size_t)row0 * Lz);
    nf4*       xdst = (nf4*)      (xcopy + (size_t)row0 * Lz);
    #pragma unroll
    for (int i = 0; i < 4; ++i) {
        int lin = i * 1024 + 2 * t;            // f4 index; 32B/lane coalesced
        nf4 f0 = xsrc[lin];
        nf4 f1 = xsrc[lin + 1];
        xdst[lin]     = f0;
        xdst[lin + 1] = f1;
        int r = lin >> 7, c16 = (lin & 127) >> 1;        // 16B-group 0..63
        uint32_t off = (uint32_t)(r * 1024 + c16 * 16) ^ (uint32_t)((r & 7) << 4);
        uint4 w;
        w.x = pk2(f0.x, f0.y); w.y = pk2(f0.z, f0.w);
        w.z = pk2(f1.x, f1.y); w.w = pk2(f1.z, f1.w);
        *(uint4*)((char*)xlds + off) = w;      // ds_write_b128
    }
    __syncthreads();                            // barrier 1

    // ---- K loop: pure compute (bv double-buffer, ds_read, MFMA) ----
    f32x4 acc[2][4];
    #pragma unroll
    for (int a = 0; a < 2; ++a)
        #pragma unroll
        for (int b = 0; b < 4; ++b)
            acc[a][b] = (f32x4){0.f, 0.f, 0.f, 0.f};

    const uint32_t s45 = (uint32_t)((lrow & 3) << 4);
    const uint32_t s6  = (uint32_t)((lrow & 4) << 4);
    const char* xb = (const char*)xlds;
    uint32_t bE[2], bO[2];
    #pragma unroll
    for (int rf = 0; rf < 2; ++rf) {
        uint32_t base = (uint32_t)((rf * 16 + lrow) * 1024 + ((lane >> 4) << 4));
        base ^= s45;
        bE[rf] = base + s6;
        bO[rf] = base - s6;
    }

    #pragma unroll
    for (int kt = 0; kt < 16; ++kt) {
        const int cur = kt & 1, nxt = cur ^ 1;
        if (kt < 15) {
            bp += 2048;
            #pragma unroll
            for (int cf = 0; cf < 4; ++cf) bv[nxt][cf] = bp[cf * 64];
        }
        bf16x8 av[2];
        #pragma unroll
        for (int rf = 0; rf < 2; ++rf)
            av[rf] = *(const bf16x8*)(xb + ((kt & 1) ? bO[rf] : bE[rf]) + kt * 64);
        #pragma unroll
        for (int cf = 0; cf < 4; ++cf)
            #pragma unroll
            for (int rf = 0; rf < 2; ++rf)
                acc[rf][cf] = __builtin_amdgcn_mfma_f32_16x16x32_bf16(
                                  av[rf], bv[cur][cf], acc[rf][cf], 0, 0, 0);
    }

    // ---- epilogue: bias + tanh*sigmoid, dot Wc, per-row 16-lane reduce ----
    const int d0 = wave * 32 + lrow;
    const int d1 = d0 + 16;
    const float ba0 = ba[d0], ba1 = ba[d1];
    const float bb0 = bb[d0], bb1 = bb[d1];
    const float wc0 = Wc[d0], wc1 = Wc[d1];

    #pragma unroll
    for (int rf = 0; rf < 2; ++rf) {
        #pragma unroll
        for (int r = 0; r < 4; ++r) {
            float pa0 = acc[rf][0][r] + ba0;
            float pa1 = acc[rf][1][r] + ba1;
            float pg0 = acc[rf][2][r] + bb0;
            float pg1 = acc[rf][3][r] + bb1;
            float ea0 = __expf(-2.f * pa0);
            float ea1 = __expf(-2.f * pa1);
            float a0 = 1.f - 2.f * ea0 * rcp_(1.f + ea0);   // tanh
            float a1 = 1.f - 2.f * ea1 * rcp_(1.f + ea1);
            float g0 = rcp_(1.f + __expf(-pg0));            // sigmoid
            float g1 = rcp_(1.f + __expf(-pg1));
            float p = a0 * g0 * wc0 + a1 * g1 * wc1;
            p += __shfl_xor(p, 1);
            p += __shfl_xor(p, 2);
            p += __shfl_xor(p, 4);
            p += __shfl_xor(p, 8);
            if (lrow == 0)
                spart[wave][rf * 16 + ((lane >> 4) << 2) + r] = p;
        }
    }
    __syncthreads();                            // barrier 2 (last)

    // ---- per-wave redundant softmax stats over the 32 rows ----
    float s = bc[0];
    #pragma unroll
    for (int w = 0; w < 8; ++w) s += spart[w][lane & 31];
    float m = s;
    #pragma unroll
    for (int o = 16; o; o >>= 1) m = fmaxf(m, __shfl_xor(m, o));
    float e = __expf(s - m);
    float es = e;
    #pragma unroll
    for (int o = 16; o; o >>= 1) es += __shfl_xor(es, o);
    if (t < 32) escore[row0 + t] = e;
    if (t == 0) { ms[wg] = m; esums[wg] = es; }

    // ---- pooled partial: group rg (rows rg*16..rg*16+15), 2 cols/thread ----
    {
        const int rg = t >> 8;           // 0 or 1
        const int c0 = (t & 255) * 2;    // col pair base
        float a0 = 0.f, a1 = 0.f;
        #pragma unroll
        for (int i = 0; i < 16; ++i) {
            int r = rg * 16 + i;
            float er = __shfl(e, r);     // lane r of own wave holds row r's e
            uint32_t off = (uint32_t)(r * 1024 + c0 * 2) ^ (uint32_t)((r & 7) << 4);
            uint32_t w = *(const uint32_t*)((const char*)xlds + off);
            a0 += er * bf2f(w & 0xffffu);
            a1 += er * bf2f(w >> 16);
        }
        *(float2*)&vs2[(((size_t)wg * 2 + rg) * 512) + c0] = make_float2(a0, a1);
    }
}

// ---------------------------------------------------------------------------
// Kernel 2: finalize. 576 blocks x 256.  (validated r6-r13)
// blocks 0..511:  A[b,n] = escore * alpha[chunk]   (16 blocks per bag)
// blocks 512..575: pooled[b,l] = sum over 128 chunks x 2 slots
// ---------------------------------------------------------------------------
__global__ __launch_bounds__(256) void finalize(
    const float* __restrict__ ms, const float* __restrict__ esums,
    const float* __restrict__ vs2, const float* __restrict__ escore,
    float* __restrict__ A, float* __restrict__ pooled)
{
    const int bid = blockIdx.x;
    const int t   = threadIdx.x;
    const bool isA = bid < 512;
    const int bag = isA ? (bid >> 4) : ((bid - 512) >> 1);
    __shared__ float alpha[128];

    if (t < 64) {                                 // one wave: 2 chunks/lane
        float ma = ms[bag * 128 + t];
        float mb = ms[bag * 128 + 64 + t];
        float M = fmaxf(ma, mb);
        #pragma unroll
        for (int o = 32; o; o >>= 1) M = fmaxf(M, __shfl_xor(M, o));
        float ea = __expf(ma - M), eb = __expf(mb - M);
        float T = esums[bag * 128 + t] * ea + esums[bag * 128 + 64 + t] * eb;
        #pragma unroll
        for (int o = 32; o; o >>= 1) T += __shfl_xor(T, o);
        alpha[t]      = ea / T;
        alpha[64 + t] = eb / T;
    }
    __syncthreads();

    if (isA) {
        int n = (bid & 15) * 256 + t;
        A[(size_t)bag * Nz + n] = escore[(size_t)bag * Nz + n] * alpha[n >> 5];
    } else {
        int col = ((bid - 512) & 1) * 256 + t;    // 0..511
        const float* base = vs2 + ((size_t)bag * 256) * 512 + col;
        float acc = 0.f;
        #pragma unroll 4
        for (int c = 0; c < 128; ++c) {
            float al = alpha[c];
            acc += al * base[(size_t)(2 * c) * 512];
            acc += al * base[(size_t)(2 * c + 1) * 512];
        }
        pooled[(size_t)bag * 512 + col] = acc;
    }
}

// ---------------------------------------------------------------------------
extern "C" void kernel_launch(void* const* d_in, const int* in_sizes, int n_in,
                              void* d_out, int out_size, void* d_ws, size_t ws_size,
                              hipStream_t stream)
{
    const float* x  = (const float*)d_in[0];
    const float* Wa = (const float*)d_in[1];
    const float* ba = (const float*)d_in[2];
    const float* Wb = (const float*)d_in[3];
    const float* bb = (const float*)d_in[4];
    const float* Wc = (const float*)d_in[5];
    const float* bc = (const float*)d_in[6];

    float* out    = (float*)d_out;
    float* A      = out;
    float* xcopy  = out + (size_t)Mz;
    float* pooled = xcopy + (size_t)Mz * Lz;

    char* ws = (char*)d_ws;
    unsigned short* packed = (unsigned short*)ws;                 // 512 KiB
    float* escore = (float*)(ws + 524288);                        // 512 KiB
    float* ms     = (float*)(ws + 1048576);                       // 16 KiB
    float* esums  = (float*)(ws + 1048576 + 16384);               // 16 KiB
    float* vs2    = (float*)(ws + 1048576 + 32768);               // 16 MiB

    pack_w      <<<128, 256, 0, stream>>>(Wa, Wb, packed);
    fused_scores<<<NWG, 512, 0, stream>>>(x, packed, ba, bb, Wc, bc,
                                          xcopy, escore, ms, esums, vs2);
    finalize    <<<576, 256, 0, stream>>>(ms, esums, vs2, escore, A, pooled);
}

// Round 16
// 177.014 us; speedup vs baseline: 2.7956x; 1.2382x over previous
//
#include <hip/hip_runtime.h>
#include <stdint.h>

#define Bz 32
#define Nz 4096
#define Lz 512
#define Mz (Bz*Nz)   // 131072 rows
#define BM 32        // rows per block
#define NWG (Mz/BM)  // 4096 blocks

typedef __attribute__((ext_vector_type(8))) short bf16x8;
typedef __attribute__((ext_vector_type(4))) float f32x4;
typedef __attribute__((ext_vector_type(4))) float nf4;

__device__ __forceinline__ uint32_t f2bf(float f) {
    union { float f; uint32_t u; } v; v.f = f;
    uint32_t u = v.u;
    u += 0x7FFFu + ((u >> 16) & 1u);   // RNE
    return u >> 16;
}

__device__ __forceinline__ uint32_t pk2(float a, float b) {
    uint32_t r;
    asm("v_cvt_pk_bf16_f32 %0, %1, %2" : "=v"(r) : "v"(a), "v"(b));
    return r;
}

__device__ __forceinline__ float rcp_(float x) { return __builtin_amdgcn_rcpf(x); }
__device__ __forceinline__ float bf2f(uint32_t u) {
    union { uint32_t u; float f; } v; v.u = u << 16; return v.f;
}

// lgkm-only barrier: spart (LDS) visibility without draining in-flight NT
// stores (vmcnt untouched). Safe: nothing after reads xcopy.
#define LGKM_BAR() asm volatile("s_waitcnt lgkmcnt(0)\n\ts_barrier" ::: "memory")

// ---------------------------------------------------------------------------
// Kernel 0: pack [Wa | Wb] into bf16 B-fragments, contiguous per (kt, wave):
// packed[((kt*8 + wave)*4 + cf)*64 + lane]; cf 0/1 = a-coltiles 2w/2w+1,
// cf 2/3 = g-coltiles 16+2w/17+2w.   (validated r5-r15)
// ---------------------------------------------------------------------------
__global__ void pack_w(const float* __restrict__ Wa, const float* __restrict__ Wb,
                       unsigned short* __restrict__ packed)
{
    int tid  = blockIdx.x * blockDim.x + threadIdx.x;   // 0..32767
    int lane = tid & 63;
    int cf   = (tid >> 6) & 3;
    int wv   = (tid >> 8) & 7;
    int kt   = tid >> 11;                               // 0..15
    int ctile = (cf < 2) ? (2 * wv + cf) : (16 + 2 * wv + (cf - 2));
    int k0  = kt * 32 + ((lane >> 4) << 3);
    int col = ctile * 16 + (lane & 15);
    const float* W = (col < 256) ? Wa : Wb;
    int c = col & 255;
    bf16x8 v;
    #pragma unroll
    for (int j = 0; j < 8; ++j) v[j] = (short)f2bf(W[(k0 + j) * 256 + c]);
    *(bf16x8*)(&packed[(size_t)tid * 8]) = v;
}

// ---------------------------------------------------------------------------
// Kernel 1: fused GEMM + gated scores + NT xcopy + pooled partials.
// r9 (validated best, wall 180.8) + (a) s_setprio around MFMA cluster,
// (b) lgkm-only final barrier. Everything else byte-identical to r9.
// ---------------------------------------------------------------------------
__global__ __launch_bounds__(512, 4) void fused_scores(
    const float* __restrict__ x, const unsigned short* __restrict__ packedW,
    const float* __restrict__ ba, const float* __restrict__ bb,
    const float* __restrict__ Wc, const float* __restrict__ bc,
    float* __restrict__ xcopy, float* __restrict__ escore,
    float* __restrict__ ms, float* __restrict__ esums,
    float* __restrict__ vs2)
{
    __shared__ unsigned short xlds[BM * Lz];   // 32 KiB, XOR-swizzled bf16
    __shared__ float spart[8][BM];             // 1 KiB

    const int wg   = blockIdx.x;       // 0..4095
    const int row0 = wg * BM;
    const int t    = threadIdx.x;
    const int wave = t >> 6;
    const int lane = t & 63;
    const int lrow = lane & 15;

    // ---- prefetch kt=0 B fragments ----
    const bf16x8* bp = (const bf16x8*)packedW + (size_t)wave * 256 + lane;
    bf16x8 bv[2][4];
    #pragma unroll
    for (int cf = 0; cf < 4; ++cf) bv[0][cf] = bp[cf * 64];

    // ---- stage: 8 batched loads, then cvt + ds_write_b128 (no stores) ----
    const nf4* xsrc = (const nf4*)(x + (size_t)row0 * Lz);
    nf4 f[8];
    #pragma unroll
    for (int i = 0; i < 4; ++i) {
        int lin = i * 1024 + 2 * t;            // f4 index; 32B/lane coalesced
        f[2 * i]     = xsrc[lin];
        f[2 * i + 1] = xsrc[lin + 1];
    }
    #pragma unroll
    for (int i = 0; i < 4; ++i) {
        int lin = i * 1024 + 2 * t;
        int r = lin >> 7, c16 = (lin & 127) >> 1;        // 16B-group 0..63
        uint32_t off = (uint32_t)(r * 1024 + c16 * 16) ^ (uint32_t)((r & 7) << 4);
        uint4 w;
        w.x = pk2(f[2*i].x, f[2*i].y);     w.y = pk2(f[2*i].z, f[2*i].w);
        w.z = pk2(f[2*i+1].x, f[2*i+1].y); w.w = pk2(f[2*i+1].z, f[2*i+1].w);
        *(uint4*)((char*)xlds + off) = w;
    }
    __syncthreads();                            // barrier 1

    // ---- K loop, with NT xcopy stores interleaved every 4 kt ----
    nf4* xdst = (nf4*)(xcopy + (size_t)row0 * Lz);

    f32x4 acc[2][4];
    #pragma unroll
    for (int a = 0; a < 2; ++a)
        #pragma unroll
        for (int b = 0; b < 4; ++b)
            acc[a][b] = (f32x4){0.f, 0.f, 0.f, 0.f};

    const uint32_t s45 = (uint32_t)((lrow & 3) << 4);
    const uint32_t s6  = (uint32_t)((lrow & 4) << 4);
    const char* xb = (const char*)xlds;
    uint32_t bE[2], bO[2];
    #pragma unroll
    for (int rf = 0; rf < 2; ++rf) {
        uint32_t base = (uint32_t)((rf * 16 + lrow) * 1024 + ((lane >> 4) << 4));
        base ^= s45;
        bE[rf] = base + s6;
        bO[rf] = base - s6;
    }

    #pragma unroll
    for (int kt = 0; kt < 16; ++kt) {
        const int cur = kt & 1, nxt = cur ^ 1;
        if (kt < 15) {
            bp += 2048;
            #pragma unroll
            for (int cf = 0; cf < 4; ++cf) bv[nxt][cf] = bp[cf * 64];
        }
        if ((kt & 3) == 1) {                   // kt = 1,5,9,13 -> pairs 0..3
            const int p = kt >> 2;
            const int lin = p * 1024 + 2 * t;
            __builtin_nontemporal_store(f[2 * p],     &xdst[lin]);
            __builtin_nontemporal_store(f[2 * p + 1], &xdst[lin + 1]);
            __builtin_amdgcn_sched_barrier(0); // keep stores spaced in time
        }
        bf16x8 av[2];
        #pragma unroll
        for (int rf = 0; rf < 2; ++rf)
            av[rf] = *(const bf16x8*)(xb + ((kt & 1) ? bO[rf] : bE[rf]) + kt * 64);
        __builtin_amdgcn_s_setprio(1);         // favor MFMA waves vs staging
        #pragma unroll
        for (int cf = 0; cf < 4; ++cf)
            #pragma unroll
            for (int rf = 0; rf < 2; ++rf)
                acc[rf][cf] = __builtin_amdgcn_mfma_f32_16x16x32_bf16(
                                  av[rf], bv[cur][cf], acc[rf][cf], 0, 0, 0);
        __builtin_amdgcn_s_setprio(0);
    }

    // ---- epilogue: bias + tanh*sigmoid, dot Wc, per-row 16-lane reduce ----
    const int d0 = wave * 32 + lrow;
    const int d1 = d0 + 16;
    const float ba0 = ba[d0], ba1 = ba[d1];
    const float bb0 = bb[d0], bb1 = bb[d1];
    const float wc0 = Wc[d0], wc1 = Wc[d1];

    #pragma unroll
    for (int rf = 0; rf < 2; ++rf) {
        #pragma unroll
        for (int r = 0; r < 4; ++r) {
            float pa0 = acc[rf][0][r] + ba0;
            float pa1 = acc[rf][1][r] + ba1;
            float pg0 = acc[rf][2][r] + bb0;
            float pg1 = acc[rf][3][r] + bb1;
            float ea0 = __expf(-2.f * pa0);
            float ea1 = __expf(-2.f * pa1);
            float a0 = 1.f - 2.f * ea0 * rcp_(1.f + ea0);   // tanh
            float a1 = 1.f - 2.f * ea1 * rcp_(1.f + ea1);
            float g0 = rcp_(1.f + __expf(-pg0));            // sigmoid
            float g1 = rcp_(1.f + __expf(-pg1));
            float p = a0 * g0 * wc0 + a1 * g1 * wc1;
            p += __shfl_xor(p, 1);
            p += __shfl_xor(p, 2);
            p += __shfl_xor(p, 4);
            p += __shfl_xor(p, 8);
            if (lrow == 0)
                spart[wave][rf * 16 + ((lane >> 4) << 2) + r] = p;
        }
    }
    LGKM_BAR();                                 // barrier 2: LDS-only drain,
                                                // NT stores stay in flight

    // ---- per-wave redundant softmax stats over the 32 rows ----
    float s = bc[0];
    #pragma unroll
    for (int w = 0; w < 8; ++w) s += spart[w][lane & 31];
    float m = s;
    #pragma unroll
    for (int o = 16; o; o >>= 1) m = fmaxf(m, __shfl_xor(m, o));
    float e = __expf(s - m);
    float es = e;
    #pragma unroll
    for (int o = 16; o; o >>= 1) es += __shfl_xor(es, o);
    if (t < 32) escore[row0 + t] = e;
    if (t == 0) { ms[wg] = m; esums[wg] = es; }

    // ---- pooled partial: group rg (rows rg*16..rg*16+15), 2 cols/thread ----
    {
        const int rg = t >> 8;           // 0 or 1
        const int c0 = (t & 255) * 2;    // col pair base
        float a0 = 0.f, a1 = 0.f;
        #pragma unroll
        for (int i = 0; i < 16; ++i) {
            int r = rg * 16 + i;
            float er = __shfl(e, r);     // lane r of own wave holds row r's e
            uint32_t off = (uint32_t)(r * 1024 + c0 * 2) ^ (uint32_t)((r & 7) << 4);
            uint32_t w = *(const uint32_t*)((const char*)xlds + off);
            a0 += er * bf2f(w & 0xffffu);
            a1 += er * bf2f(w >> 16);
        }
        *(float2*)&vs2[(((size_t)wg * 2 + rg) * 512) + c0] = make_float2(a0, a1);
    }
}

// ---------------------------------------------------------------------------
// Kernel 2: finalize. 576 blocks x 256.  (validated r6-r15)
// blocks 0..511:  A[b,n] = escore * alpha[chunk]   (16 blocks per bag)
// blocks 512..575: pooled[b,l] = sum over 128 chunks x 2 slots
// ---------------------------------------------------------------------------
__global__ __launch_bounds__(256) void finalize(
    const float* __restrict__ ms, const float* __restrict__ esums,
    const float* __restrict__ vs2, const float* __restrict__ escore,
    float* __restrict__ A, float* __restrict__ pooled)
{
    const int bid = blockIdx.x;
    const int t   = threadIdx.x;
    const bool isA = bid < 512;
    const int bag = isA ? (bid >> 4) : ((bid - 512) >> 1);
    __shared__ float alpha[128];

    if (t < 64) {                                 // one wave: 2 chunks/lane
        float ma = ms[bag * 128 + t];
        float mb = ms[bag * 128 + 64 + t];
        float M = fmaxf(ma, mb);
        #pragma unroll
        for (int o = 32; o; o >>= 1) M = fmaxf(M, __shfl_xor(M, o));
        float ea = __expf(ma - M), eb = __expf(mb - M);
        float T = esums[bag * 128 + t] * ea + esums[bag * 128 + 64 + t] * eb;
        #pragma unroll
        for (int o = 32; o; o >>= 1) T += __shfl_xor(T, o);
        alpha[t]      = ea / T;
        alpha[64 + t] = eb / T;
    }
    __syncthreads();

    if (isA) {
        int n = (bid & 15) * 256 + t;
        A[(size_t)bag * Nz + n] = escore[(size_t)bag * Nz + n] * alpha[n >> 5];
    } else {
        int col = ((bid - 512) & 1) * 256 + t;    // 0..511
        const float* base = vs2 + ((size_t)bag * 256) * 512 + col;
        float acc = 0.f;
        #pragma unroll 4
        for (int c = 0; c < 128; ++c) {
            float al = alpha[c];
            acc += al * base[(size_t)(2 * c) * 512];
            acc += al * base[(size_t)(2 * c + 1) * 512];
        }
        pooled[(size_t)bag * 512 + col] = acc;
    }
}

// ---------------------------------------------------------------------------
extern "C" void kernel_launch(void* const* d_in, const int* in_sizes, int n_in,
                              void* d_out, int out_size, void* d_ws, size_t ws_size,
                              hipStream_t stream)
{
    const float* x  = (const float*)d_in[0];
    const float* Wa = (const float*)d_in[1];
    const float* ba = (const float*)d_in[2];
    const float* Wb = (const float*)d_in[3];
    const float* bb = (const float*)d_in[4];
    const float* Wc = (const float*)d_in[5];
    const float* bc = (const float*)d_in[6];

    float* out    = (float*)d_out;
    float* A      = out;
    float* xcopy  = out + (size_t)Mz;
    float* pooled = xcopy + (size_t)Mz * Lz;

    char* ws = (char*)d_ws;
    unsigned short* packed = (unsigned short*)ws;                 // 512 KiB
    float* escore = (float*)(ws + 524288);                        // 512 KiB
    float* ms     = (float*)(ws + 1048576);                       // 16 KiB
    float* esums  = (float*)(ws + 1048576 + 16384);               // 16 KiB
    float* vs2    = (float*)(ws + 1048576 + 32768);               // 16 MiB

    pack_w      <<<128, 256, 0, stream>>>(Wa, Wb, packed);
    fused_scores<<<NWG, 512, 0, stream>>>(x, packed, ba, bb, Wc, bc,
                                          xcopy, escore, ms, esums, vs2);
    finalize    <<<576, 256, 0, stream>>>(ms, esums, vs2, escore, A, pooled);
}